// Round 2
// baseline (843.876 us; speedup 1.0000x reference)
//
#include <hip/hip_runtime.h>

#define NK 8
#define NV 8

// ── ROUND-6: OCCUPANCY ×2 (vec4 → vec2 per thread) — still REP=4 diagnostic ─
// R5 counters (REP=4 surfaced dpa_kernel): 340.6us/4reps = 85us/rep effective
// (L3-flattered; true single-rep >= that). VALUBusy 3.1%, bank-conflict 0,
// VGPR 64, Occupancy 45%. Diagnosis: pure streaming kernel, BW set by
// bytes-in-flight = waves/CU x dest-VGPRs x 4B. Occupancy is GRID-starved:
// 262,144 threads = 4096 waves = exactly 16 waves/CU (50% cap). Per-wave
// depth is already reg-capped at ~64 VGPRs.
// Fix: one vec2 (8B) per thread -> 524,288 threads = 32 waves/CU (~95%),
// same VGPR/wave -> ~2x in-flight bytes/CU. Coalescing intact (512B/wave
// per load instr); instruction rate irrelevant at 3% VALUBusy.
// launch_bounds(256,8) pins VGPR<=64 so 8 waves/SIMD are schedulable.
// Predict: dispatch 340->~250us (rep ~60-68us ~= 59us floor), occupancy ~90.
// If confirmed -> REP=1 commit next round, expect harness dur ~365-385us.
// ─────────────────────────────────────────────────────────────────────────────

#define REP 4  // DIAGNOSTIC ONLY — revert to 1 once per-rep time confirmed

typedef float vf2 __attribute__((ext_vector_type(2)));

__device__ __forceinline__ vf2 ntload2(const float* p) {
    return __builtin_nontemporal_load(reinterpret_cast<const vf2*>(p));
}
__device__ __forceinline__ void ntstore2(float* p, vf2 v) {
    __builtin_nontemporal_store(v, reinterpret_cast<vf2*>(p));
}

__global__ __launch_bounds__(256, 8) void dpa_kernel(const float* __restrict__ inp,
                                                     float* __restrict__ out) {
    constexpr int HW = 512 * 512;          // 262144 floats per channel plane
    constexpr int HW2 = HW / 2;            // 131072 vec2's per plane
    constexpr int C = NK + NK * NV + NV;   // 80
    const float scale = 0.35355339059327373f; // 1/sqrt(8)

    int idx = blockIdx.x * blockDim.x + threadIdx.x;
    int b  = idx >> 17;                    // HW2 = 2^17 vec2's per batch-plane
    int s2 = idx & (HW2 - 1);
    const float* pin = inp + (size_t)b * C * HW + (size_t)s2 * 2;
    float* pout = out + (size_t)b * NV * HW + (size_t)s2 * 2;

    for (int rep = 0; rep < REP; ++rep) {
        // Compiler-level memory barrier: forces every rep to re-issue the NT
        // loads (defeats LICM/CSE across reps so traffic really is 4x).
        asm volatile("" ::: "memory");

        // ── q preload: 8 loads (16 VGPRs), resident for the accumulation ──
        vf2 q[NK];
#pragma unroll
        for (int kk = 0; kk < NK; ++kk) q[kk] = ntload2(pin + (size_t)kk * HW);

        vf2 qk[NV];
#pragma unroll
        for (int v = 0; v < NV; ++v) qk[v] = (vf2)(0.f);

        // ── qk[v] = sum_k q[k]*K[k][v]; 64 k-loads, ascending addresses,
        //    full unroll -> scheduler batches loads to the VGPR budget. ──
#pragma unroll
        for (int kk = 0; kk < NK; ++kk) {
#pragma unroll
            for (int v = 0; v < NV; ++v) {
                vf2 kv = ntload2(pin + (size_t)(NK + kk * NV + v) * HW);
                qk[v] = q[kk] * kv + qk[v];   // vector fma
            }
        }

        // ── V prefetch before softmax VALU: latency hides under max/exp. ──
        vf2 vv[NV];
#pragma unroll
        for (int v = 0; v < NV; ++v)
            vv[v] = ntload2(pin + (size_t)(NK + NK * NV + v) * HW);

        // scale
#pragma unroll
        for (int v = 0; v < NV; ++v) qk[v] *= scale;

        // componentwise max over v
        vf2 mx = qk[0];
#pragma unroll
        for (int v = 1; v < NV; ++v) {
            mx.x = fmaxf(mx.x, qk[v].x);
            mx.y = fmaxf(mx.y, qk[v].y);
        }

        // exp and sum (componentwise)
        vf2 sum = (vf2)(0.f);
#pragma unroll
        for (int v = 0; v < NV; ++v) {
            qk[v].x = __expf(qk[v].x - mx.x);
            qk[v].y = __expf(qk[v].y - mx.y);
            sum += qk[v];
        }
        vf2 inv;
        inv.x = 1.0f / sum.x;
        inv.y = 1.0f / sum.y;

        // out[b][v][h][w] = softmax * vchan
#pragma unroll
        for (int v = 0; v < NV; ++v)
            ntstore2(pout + (size_t)v * HW, qk[v] * inv * vv[v]);
    }
}

extern "C" void kernel_launch(void* const* d_in, const int* in_sizes, int n_in,
                              void* d_out, int out_size, void* d_ws, size_t ws_size,
                              hipStream_t stream) {
    const float* inp = (const float*)d_in[0];
    float* out = (float*)d_out;

    constexpr int HW = 512 * 512;
    constexpr int C = NK + NK * NV + NV; // 80
    int B = in_sizes[0] / (C * HW);      // 4

    int nThreads = B * (HW / 2);         // one vec2 per thread
    dim3 block(256);
    dim3 grid(nThreads / 256);
    dpa_kernel<<<grid, block, 0, stream>>>(inp, out);
}

// Round 3
// 743.772 us; speedup vs baseline: 1.1346x; 1.1346x over previous
//
#include <hip/hip_runtime.h>

#define NK 8
#define NV 8

// ── ROUND-7: DROP NON-TEMPORAL HINTS (A/B vs R5/R6) — still REP=4 diagnostic ─
// R6 falsified the occupancy theory: 45%->90% waves/CU moved HBM-actual BW
// not at all (3.25 -> 3.18 TB/s). The cap is in the memory path, not
// concurrency. New evidence: WRITE_SIZE amplification that scales with store
// narrowness — NT-vec4 = 1.75x ideal, NT-vec2 = 3.15x ideal. Signature of NT
// stores bypassing L2 write-combining and emitting partial-line masked bursts.
// NT loads likewise ride a no-allocate/reduced-buffer TCC path (plausible
// ~half-rate throttle): both R5 and R6 pin at ~3.2 TB/s while plain-store
// fillBuffer does 6.6 and plain float4-copy does 6.3 TB/s. NT was inherited
// from the prior session WITHOUT an isolated A/B. This round isolates it:
// identical structure to R5 (vec4/thread, q-preload, V-prefetch, REP=4),
// plain loads/stores only.
// Predict: WRITE_SIZE 424 -> ~134-145 MB (near-certain). If NT was the BW
// cap: dispatch 526 -> ~230-280us (rep ~60-70us ~= 59us floor) -> REP=1 next
// round. If BW stays ~3.2 TB/s: cap is the 80-stream 1MB-stride gather
// pattern -> next lever is thread coarsening for DRAM row locality.
// ─────────────────────────────────────────────────────────────────────────────

#define REP 4  // DIAGNOSTIC ONLY — revert to 1 once per-rep time confirmed

typedef float vf4 __attribute__((ext_vector_type(4)));

__device__ __forceinline__ vf4 ld4(const float* p) {
    return *reinterpret_cast<const vf4*>(p);
}
__device__ __forceinline__ void st4(float* p, vf4 v) {
    *reinterpret_cast<vf4*>(p) = v;
}

__global__ __launch_bounds__(256, 4) void dpa_kernel(const float* __restrict__ inp,
                                                     float* __restrict__ out) {
    constexpr int HW = 512 * 512;          // 262144 floats per channel plane
    constexpr int C = NK + NK * NV + NV;   // 80
    const float scale = 0.35355339059327373f; // 1/sqrt(8)

    int idx = blockIdx.x * blockDim.x + threadIdx.x;
    int b  = idx >> 16;          // HW/4 = 65536 vec4's per batch-plane
    int s4 = idx & 65535;
    const float* pin = inp + (size_t)b * C * HW + (size_t)s4 * 4;
    float* pout = out + (size_t)b * NV * HW + (size_t)s4 * 4;

    for (int rep = 0; rep < REP; ++rep) {
        // Compiler-level memory barrier: forces every rep to re-issue loads
        // and commit stores (defeats cross-rep LICM/CSE/DSE so traffic is 4x).
        asm volatile("" ::: "memory");

        // ── q preload: 8 loads (32 VGPRs), resident for the accumulation ──
        vf4 q[NK];
#pragma unroll
        for (int kk = 0; kk < NK; ++kk) q[kk] = ld4(pin + (size_t)kk * HW);

        vf4 qk[NV];
#pragma unroll
        for (int v = 0; v < NV; ++v) qk[v] = (vf4)(0.f);

        // ── qk[v] = sum_k q[k]*K[k][v]; 64 k-loads, ascending addresses,
        //    full unroll -> scheduler batches loads to the VGPR budget. ──
#pragma unroll
        for (int kk = 0; kk < NK; ++kk) {
#pragma unroll
            for (int v = 0; v < NV; ++v) {
                vf4 kv = ld4(pin + (size_t)(NK + kk * NV + v) * HW);
                qk[v] = q[kk] * kv + qk[v];   // vector fma
            }
        }

        // ── V prefetch before softmax VALU: latency hides under max/exp. ──
        vf4 vv[NV];
#pragma unroll
        for (int v = 0; v < NV; ++v)
            vv[v] = ld4(pin + (size_t)(NK + NK * NV + v) * HW);

        // scale
#pragma unroll
        for (int v = 0; v < NV; ++v) qk[v] *= scale;

        // componentwise max over v
        vf4 mx = qk[0];
#pragma unroll
        for (int v = 1; v < NV; ++v) {
            mx.x = fmaxf(mx.x, qk[v].x); mx.y = fmaxf(mx.y, qk[v].y);
            mx.z = fmaxf(mx.z, qk[v].z); mx.w = fmaxf(mx.w, qk[v].w);
        }

        // exp and sum (componentwise)
        vf4 sum = (vf4)(0.f);
#pragma unroll
        for (int v = 0; v < NV; ++v) {
            qk[v].x = __expf(qk[v].x - mx.x);
            qk[v].y = __expf(qk[v].y - mx.y);
            qk[v].z = __expf(qk[v].z - mx.z);
            qk[v].w = __expf(qk[v].w - mx.w);
            sum += qk[v];
        }
        vf4 inv;
        inv.x = 1.0f / sum.x; inv.y = 1.0f / sum.y;
        inv.z = 1.0f / sum.z; inv.w = 1.0f / sum.w;

        // out[b][v][h][w] = softmax * vchan
#pragma unroll
        for (int v = 0; v < NV; ++v)
            st4(pout + (size_t)v * HW, qk[v] * inv * vv[v]);
    }
}

extern "C" void kernel_launch(void* const* d_in, const int* in_sizes, int n_in,
                              void* d_out, int out_size, void* d_ws, size_t ws_size,
                              hipStream_t stream) {
    const float* inp = (const float*)d_in[0];
    float* out = (float*)d_out;

    constexpr int HW = 512 * 512;
    constexpr int C = NK + NK * NV + NV; // 80
    int B = in_sizes[0] / (C * HW);      // 4

    int nThreads = B * (HW / 4);
    dim3 block(256);
    dim3 grid(nThreads / 256);
    dpa_kernel<<<grid, block, 0, stream>>>(inp, out);
}

// Round 4
// 652.028 us; speedup vs baseline: 1.2942x; 1.1407x over previous
//
#include <hip/hip_runtime.h>

#define NK 8
#define NV 8

// ── ROUND-8: BREAK THE IN-FLIGHT CAP — global_load_lds per-wave FIFO ─────────
// Post-mortems: occupancy 45->90% didn't move BW (R6); NT->plain made it
// WORSE (R7: 3.25->2.6 TB/s, WRITE amp 1.75x unchanged -> not an NT artifact;
// R6's vec2 was confounded by forced VGPR=32 spills). Every reg-load config
// pins at ~3.2 TB/s because outstanding bytes are DEST-VGPR-capped:
// ~10 loads x 16B x 16 waves/CU ~= 3-5 KB/CU in flight, and waves/CU x
// VGPR/wave is a ~constant product. At this pattern's latency (~900cy; 88
// 1MB-strided streams x ~1e3 resident blocks = DRAM row thrash) that IS
// ~3 TB/s. Little's law needs ~9-15 KB/CU for 6.3 TB/s.
// Fix (guide §5.5 T3/T4 mechanism): global_load_lds — outstanding ops are
// vmcnt-counted (<=63/wave), zero VGPR cost, 1KB/instr/wave. Per-wave PRIVATE
// LDS FIFO: each wave stages its own 1KB slice of each K-plane and reads back
// only its own slice -> no __syncthreads anywhere; counted vmcnt(8/16) only.
// LDS = 2buf x 4waves x 8planes x 1KB = 64KB -> 2 blocks/CU (8 waves/CU,
// 25% occ — intentionally testing that flight depth, not occupancy, is what
// matters). q preloaded to regs; V loaded to regs under last compute groups.
// REP=6 diagnostic (at >=5.5 TB/s a REP=4 dispatch would hide under the
// 203us harness fills). Predict: hbm_gbps 3251 -> >=5500, dispatch ~300-330us
// (fail mode: ~560us at 3.2 TB/s -> pattern-bound, commit R5@REP=1).
// ─────────────────────────────────────────────────────────────────────────────

#define REP 6  // DIAGNOSTIC ONLY — revert to 1 once counters are read

typedef float vf4 __attribute__((ext_vector_type(4)));

__device__ __forceinline__ vf4 ntload4(const float* p) {
    return __builtin_nontemporal_load(reinterpret_cast<const vf4*>(p));
}
__device__ __forceinline__ void ntstore4(float* p, vf4 v) {
    __builtin_nontemporal_store(v, reinterpret_cast<vf4*>(p));
}

// Async global->LDS, 16B per lane. LDS dest = wave-uniform base + lane*16
// (HW-added); global src is per-lane. vmcnt-tracked.
__device__ __forceinline__ void stage16(const float* g, char* l) {
    __builtin_amdgcn_global_load_lds(
        (const __attribute__((address_space(1))) unsigned int*)g,
        (__attribute__((address_space(3))) unsigned int*)l,
        16, 0, 0);
}

__global__ __launch_bounds__(256, 2) void dpa_kernel(const float* __restrict__ inp,
                                                     float* __restrict__ out) {
    constexpr int HW = 512 * 512;          // floats per channel plane (1MB)
    constexpr int C = NK + NK * NV + NV;   // 80
    const float scale = 0.35355339059327373f; // 1/sqrt(8)

    // [buf:2][wave:4][plane:8][1024B] — per-wave private FIFO, no sharing.
    __shared__ __attribute__((aligned(16))) char smem[2 * 4 * NV * 1024];

    const int tid  = threadIdx.x;
    const int wave = tid >> 6;
    const int lane16 = (tid & 63) * 16;

    int idx = blockIdx.x * 256 + tid;
    int b  = idx >> 16;                    // HW/4 = 2^16 vec4s per batch-plane
    int s4 = idx & 65535;
    const float* pin = inp + (size_t)b * C * HW + (size_t)s4 * 4;
    float* pout = out + (size_t)b * NV * HW + (size_t)s4 * 4;

    char* lbase = smem + wave * (NV * 1024);   // + buf*32768 + plane*1024

    for (int rep = 0; rep < REP; ++rep) {
        asm volatile("" ::: "memory");  // defeat cross-rep LICM/CSE/DSE

        // ── q preload: 8 NT reg loads (32 VGPR), oldest vmcnt events ──
        vf4 q[NK];
#pragma unroll
        for (int kk = 0; kk < NK; ++kk) q[kk] = ntload4(pin + (size_t)kk * HW);

        // ── stage K-group 0 into buf0 ──
#pragma unroll
        for (int v = 0; v < NV; ++v)
            stage16(pin + (size_t)(NK + v) * HW, lbase + v * 1024);

        vf4 qk[NV];
#pragma unroll
        for (int v = 0; v < NV; ++v) qk[v] = (vf4)(0.f);

        vf4 vv[NV];

#pragma unroll
        for (int kk = 0; kk < NK; ++kk) {
            const int cur = kk & 1;
            const int nxt = cur ^ 1;

            // issue next K-group stage before consuming current (T14 pattern)
            if (kk < NK - 1) {
#pragma unroll
                for (int v = 0; v < NV; ++v)
                    stage16(pin + (size_t)(NK + (kk + 1) * NV + v) * HW,
                            lbase + nxt * 32768 + v * 1024);
            }
            // V reg-loads issued under the last two compute groups
            if (kk == NK - 2) {
#pragma unroll
                for (int v = 0; v < NV; ++v)
                    vv[v] = ntload4(pin + (size_t)(NK + NK * NV + v) * HW);
            }

            // counted wait: group kk complete; younger ops stay in flight
            if (kk < NK - 2)       asm volatile("s_waitcnt vmcnt(8)" ::: "memory");
            else if (kk == NK - 2) asm volatile("s_waitcnt vmcnt(16)" ::: "memory");
            else                   asm volatile("s_waitcnt vmcnt(8)" ::: "memory");
            __builtin_amdgcn_sched_barrier(0);  // rule #18: pin reads below wait

#pragma unroll
            for (int v = 0; v < NV; ++v) {
                vf4 kv = *reinterpret_cast<const vf4*>(
                    lbase + cur * 32768 + v * 1024 + lane16);
                qk[v] = q[kk] * kv + qk[v];   // vector fma
            }
        }

        // ── softmax over v (componentwise) ──
#pragma unroll
        for (int v = 0; v < NV; ++v) qk[v] *= scale;

        vf4 mx = qk[0];
#pragma unroll
        for (int v = 1; v < NV; ++v) {
            mx.x = fmaxf(mx.x, qk[v].x); mx.y = fmaxf(mx.y, qk[v].y);
            mx.z = fmaxf(mx.z, qk[v].z); mx.w = fmaxf(mx.w, qk[v].w);
        }

        vf4 sum = (vf4)(0.f);
#pragma unroll
        for (int v = 0; v < NV; ++v) {
            qk[v].x = __expf(qk[v].x - mx.x);
            qk[v].y = __expf(qk[v].y - mx.y);
            qk[v].z = __expf(qk[v].z - mx.z);
            qk[v].w = __expf(qk[v].w - mx.w);
            sum += qk[v];
        }
        vf4 inv;
        inv.x = 1.0f / sum.x; inv.y = 1.0f / sum.y;
        inv.z = 1.0f / sum.z; inv.w = 1.0f / sum.w;

        // ── out[b][v][h][w] = softmax * vchan ──
#pragma unroll
        for (int v = 0; v < NV; ++v)
            ntstore4(pout + (size_t)v * HW, qk[v] * inv * vv[v]);
    }
}

extern "C" void kernel_launch(void* const* d_in, const int* in_sizes, int n_in,
                              void* d_out, int out_size, void* d_ws, size_t ws_size,
                              hipStream_t stream) {
    const float* inp = (const float*)d_in[0];
    float* out = (float*)d_out;

    constexpr int HW = 512 * 512;
    constexpr int C = NK + NK * NV + NV; // 80
    int B = in_sizes[0] / (C * HW);      // 4

    int nThreads = B * (HW / 4);         // one vec4 per thread
    dim3 block(256);
    dim3 grid(nThreads / 256);
    dpa_kernel<<<grid, block, 0, stream>>>(inp, out);
}